// Round 25
// baseline (457.752 us; speedup 1.0000x reference)
//
#include <hip/hip_runtime.h>
#include <hip/hip_bf16.h>
#include <cstddef>

#define V_N 30000
#define E_N 480000
#define HID 256
#define HEADS 4
#define HD 64
#define M_ROWS 1024   // 2*512
#define K_DIM 30000
#define K_PAD 30080   // 47 * 640
#define CHUNK_EL 640  // K elements per GEMM block
#define NSTEP 10      // 640 / 64
#define SK_MFMA 47
#define NR 8          // owner ranges (XCD-owned writes)
#define VR (V_N / NR) // 3750
#define UNR 8         // gather MLP depth
#define SLOTS 64      // fixed CSR arena slots per vertex (mean deg 16, sigma 4)
#define GRAN (K_PAD / 8)          // 3760 granules per X row
#define XTASKS (M_ROWS * GRAN)    // 3,850,240 cvt_X granule tasks
#define XBLK 7520                 // cvt_X blocks: XBLK*256*2 == XTASKS
#define NEG_SLOPE 0.2f
#define EPS_F 1e-9f

#if defined(__has_builtin)
#if __has_builtin(__builtin_amdgcn_fdot2_f32_bf16) && __has_builtin(__builtin_amdgcn_perm)
#define HAS_DOT2 1
#endif
#endif

typedef __attribute__((ext_vector_type(8))) short bf16x8;
typedef __attribute__((ext_vector_type(4))) float f32x4;
typedef __attribute__((ext_vector_type(8))) unsigned short u16x8;
typedef __attribute__((ext_vector_type(4))) unsigned short u16x4;
#ifdef HAS_DOT2
typedef __attribute__((ext_vector_type(2))) __bf16 bf16x2v;
#endif

__device__ inline unsigned short f2bf_rtn(float f) {
  unsigned u = __float_as_uint(f);
  unsigned r = u + 0x7fffu + ((u >> 16) & 1u);
  return (unsigned short)(r >> 16);
}
__device__ inline float bf2f(unsigned short h) {
  return __uint_as_float(((unsigned)h) << 16);
}

__device__ __forceinline__ void gload_lds16(const void* g, void* l) {
  __builtin_amdgcn_global_load_lds(
      (const __attribute__((address_space(1))) void*)g,
      (__attribute__((address_space(3))) void*)l, 16, 0, 0);
}

// ---------- fused prep: arena fill (bid<15000) + cvt_W (15000..22499) + cvt_X ----------
__global__ __launch_bounds__(256) void k_fill_cvt(
    const int* __restrict__ s0g, const int* __restrict__ d0g,
    const int* __restrict__ s1g, const int* __restrict__ d1g,
    const float* __restrict__ val0, const float* __restrict__ val1,
    int* __restrict__ cnt, int2* __restrict__ csr_s, int* __restrict__ csr_d,
    const float* __restrict__ W0src, const float* __restrict__ W1src,
    unsigned short* __restrict__ W0dst, unsigned short* __restrict__ W1dst,
    const float* __restrict__ X, unsigned short* __restrict__ Xhi) {
  const int bid = blockIdx.x;
  if (bid < 15000) {
    const int r = bid & 7;
    const int e = (bid >> 3) * 256 + threadIdx.x;
    if (e >= E_N) return;
    const int v0 = r * VR, v1 = v0 + VR;
    int k, p;
    k = s0g[e];
    if (k >= v0 && k < v1) {
      p = atomicAdd(&cnt[0 * V_N + k], 1);
      if (p < SLOTS) csr_s[((size_t)0 * V_N + k) * SLOTS + p] = make_int2(d0g[e], __float_as_int(val0[e]));
    }
    k = d0g[e];
    if (k >= v0 && k < v1) {
      p = atomicAdd(&cnt[1 * V_N + k], 1);
      if (p < SLOTS) csr_d[((size_t)0 * V_N + k) * SLOTS + p] = s0g[e];
    }
    k = s1g[e];
    if (k >= v0 && k < v1) {
      p = atomicAdd(&cnt[2 * V_N + k], 1);
      if (p < SLOTS) csr_s[((size_t)1 * V_N + k) * SLOTS + p] = make_int2(d1g[e], __float_as_int(val1[e]));
    }
    k = d1g[e];
    if (k >= v0 && k < v1) {
      p = atomicAdd(&cnt[3 * V_N + k], 1);
      if (p < SLOTS) csr_d[((size_t)1 * V_N + k) * SLOTS + p] = s1g[e];
    }
  } else if (bid < 22500) {
    const int b = bid - 15000;          // 0..7499
    const int wg = b % 3750;
    const int g = b / 3750;
    const float* Wsrc = g ? W1src : W0src;
    unsigned short* Wdst = g ? W1dst : W0dst;
    size_t i = ((size_t)wg * 256 + threadIdx.x) * 8;
    const float4* p = reinterpret_cast<const float4*>(Wsrc + i);
    float4 x0 = p[0], x1 = p[1];
    float xs[8] = {x0.x, x0.y, x0.z, x0.w, x1.x, x1.y, x1.z, x1.w};
    u16x8 o;
    #pragma unroll
    for (int j = 0; j < 8; ++j) o[j] = f2bf_rtn(xs[j]);
    *reinterpret_cast<u16x8*>(Wdst + i) = o;
  } else {
    const int b = bid - 22500;          // 0..XBLK-1
    #pragma unroll
    for (int it = 0; it < 2; ++it) {
      int idx = (b * 256 + threadIdx.x) + it * (XBLK * 256);
      if (idx >= XTASKS) break;
      int row = idx / GRAN;
      int g = idx - row * GRAN;
      int k0 = g * 8;
      u16x8 hi;
      if (k0 < K_DIM) {
        const float4* p = reinterpret_cast<const float4*>(X + (size_t)row * K_DIM + k0);
        float4 x0 = p[0], x1 = p[1];
        float xs[8] = {x0.x, x0.y, x0.z, x0.w, x1.x, x1.y, x1.z, x1.w};
        #pragma unroll
        for (int j = 0; j < 8; ++j) hi[j] = f2bf_rtn(xs[j]);
      } else {
        #pragma unroll
        for (int j = 0; j < 8; ++j) hi[j] = 0;
      }
      int gs = (g & ~7) | ((g & 7) ^ (row & 7));
      *reinterpret_cast<u16x8*>(Xhi + (size_t)row * K_PAD + gs * 8) = hi;
    }
  }
}

// ---------- Phase 1+2: H gather, BOTH graphs (blockIdx.y = g), 8-wide MLP ----------
__global__ __launch_bounds__(256) void k_gather_H(
    const int* __restrict__ cnt, const int2* __restrict__ csr_s,
    const unsigned short* __restrict__ Wb0, const unsigned short* __restrict__ Wb1,
    const float* __restrict__ a0v, const float* __restrict__ a1v,
    unsigned short* __restrict__ Hb, float* __restrict__ s0, float* __restrict__ s1) {
  const int g = blockIdx.y;
  const unsigned short* Wb = g ? Wb1 : Wb0;
  const float* a = g ? a1v : a0v;
  unsigned short* Hbg = Hb + (size_t)g * V_N * HID;
  float* s0g = s0 + (size_t)g * V_N * HEADS;
  float* s1g = s1 + (size_t)g * V_N * HEADS;

  int v = blockIdx.x * 4 + (threadIdx.x >> 6);
  if (v >= V_N) return;
  int lane = threadIdx.x & 63;
  const int2* csr = csr_s + ((size_t)g * V_N + v) * SLOTS;
  int n = cnt[(g * 2) * V_N + v];
  n = n < SLOTS ? n : SLOTS;
  const u16x4* W4 = reinterpret_cast<const u16x4*>(Wb);
  float4 acc = {0.f, 0.f, 0.f, 0.f};
  int dcur[UNR]; float fcur[UNR];
  #pragma unroll
  for (int q = 0; q < UNR; ++q) {
    dcur[q] = 0; fcur[q] = 0.f;
    if (q < n) { int2 pl = csr[q]; dcur[q] = pl.x; fcur[q] = __int_as_float(pl.y); }
  }
  for (int i = 0; i < n; i += UNR) {
    int dnxt[UNR]; float fnxt[UNR];
    #pragma unroll
    for (int q = 0; q < UNR; ++q) {
      dnxt[q] = 0; fnxt[q] = 0.f;
      if (i + UNR + q < n) { int2 pl = csr[i + UNR + q]; dnxt[q] = pl.x; fnxt[q] = __int_as_float(pl.y); }
    }
    u16x4 wv[UNR];
    #pragma unroll
    for (int q = 0; q < UNR; ++q) wv[q] = W4[(size_t)dcur[q] * 64 + lane];
#ifdef HAS_DOT2
    #pragma unroll
    for (int q = 0; q < UNR; q += 2) {
      unsigned fp;
      asm("v_cvt_pk_bf16_f32 %0, %1, %2" : "=v"(fp) : "v"(fcur[q]), "v"(fcur[q + 1]));
      uint2 ua = __builtin_bit_cast(uint2, wv[q]);
      uint2 ub = __builtin_bit_cast(uint2, wv[q + 1]);
      unsigned p0 = __builtin_amdgcn_perm(ua.x, ub.x, 0x01000504u);
      unsigned p1 = __builtin_amdgcn_perm(ua.x, ub.x, 0x03020706u);
      unsigned p2 = __builtin_amdgcn_perm(ua.y, ub.y, 0x01000504u);
      unsigned p3 = __builtin_amdgcn_perm(ua.y, ub.y, 0x03020706u);
      bf16x2v fv = __builtin_bit_cast(bf16x2v, fp);
      acc.x = __builtin_amdgcn_fdot2_f32_bf16(fv, __builtin_bit_cast(bf16x2v, p0), acc.x, false);
      acc.y = __builtin_amdgcn_fdot2_f32_bf16(fv, __builtin_bit_cast(bf16x2v, p1), acc.y, false);
      acc.z = __builtin_amdgcn_fdot2_f32_bf16(fv, __builtin_bit_cast(bf16x2v, p2), acc.z, false);
      acc.w = __builtin_amdgcn_fdot2_f32_bf16(fv, __builtin_bit_cast(bf16x2v, p3), acc.w, false);
    }
#else
    #pragma unroll
    for (int q = 0; q < UNR; ++q) {
      acc.x += fcur[q] * bf2f(wv[q][0]);
      acc.y += fcur[q] * bf2f(wv[q][1]);
      acc.z += fcur[q] * bf2f(wv[q][2]);
      acc.w += fcur[q] * bf2f(wv[q][3]);
    }
#endif
    #pragma unroll
    for (int q = 0; q < UNR; ++q) { dcur[q] = dnxt[q]; fcur[q] = fnxt[q]; }
  }
  u16x4 hb;
  hb[0] = f2bf_rtn(acc.x); hb[1] = f2bf_rtn(acc.y);
  hb[2] = f2bf_rtn(acc.z); hb[3] = f2bf_rtn(acc.w);
  *(reinterpret_cast<u16x4*>(Hbg) + (size_t)v * 64 + lane) = hb;
  int h = lane >> 4, dd = (lane & 15) * 4;
  const float* ah = a + h * (2 * HD);
  float p0 = acc.x * ah[dd] + acc.y * ah[dd + 1] + acc.z * ah[dd + 2] + acc.w * ah[dd + 3];
  float p1 = acc.x * ah[HD + dd] + acc.y * ah[HD + dd + 1] + acc.z * ah[HD + dd + 2] + acc.w * ah[HD + dd + 3];
  #pragma unroll
  for (int off = 1; off < 16; off <<= 1) {
    p0 += __shfl_xor(p0, off);
    p1 += __shfl_xor(p1, off);
  }
  if ((lane & 15) == 0) {
    s0g[v * HEADS + h] = p0;
    s1g[v * HEADS + h] = p1;
  }
}

// ---------- Phase 3+4: softmax + aggregation; writes bf16 Hsum directly ----------
__global__ __launch_bounds__(256) void k_fused_agg(
    const int* __restrict__ cnt, const int* __restrict__ csr_d,
    const float* __restrict__ s0, const float* __restrict__ s1,
    const unsigned short* __restrict__ Hb, unsigned short* __restrict__ Hsb) {
  int v = blockIdx.x * 4 + (threadIdx.x >> 6);
  if (v >= V_N) return;
  int lane = threadIdx.x & 63;
  int hB = lane >> 4;
  float4 tot = {0.f, 0.f, 0.f, 0.f};
  #pragma unroll 1
  for (int g = 0; g < 2; ++g) {
    const int* csr = csr_d + ((size_t)g * V_N + v) * SLOTS;
    const float* s0g = s0 + (size_t)g * V_N * HEADS;
    const u16x4* H4 = reinterpret_cast<const u16x4*>(Hb + (size_t)g * V_N * HID);
    const float s1B = s1[(size_t)g * V_N * HEADS + v * HEADS + hB];
    int n = cnt[(g * 2 + 1) * V_N + v];
    n = n < SLOTS ? n : SLOTS;
    float4 acc = {0.f, 0.f, 0.f, 0.f};
    float dsum = 0.f;
    int svc[UNR]; float pc[UNR];
    #pragma unroll
    for (int q = 0; q < UNR; ++q) {
      svc[q] = 0; pc[q] = -1e30f;
      if (q < n) { svc[q] = csr[q]; pc[q] = s0g[svc[q] * HEADS + hB]; }
    }
    for (int i = 0; i < n; i += UNR) {
      int svn[UNR]; float pn[UNR];
      #pragma unroll
      for (int q = 0; q < UNR; ++q) {
        svn[q] = 0; pn[q] = -1e30f;
        if (i + UNR + q < n) { svn[q] = csr[i + UNR + q]; pn[q] = s0g[svn[q] * HEADS + hB]; }
      }
      u16x4 hv[UNR];
      #pragma unroll
      for (int q = 0; q < UNR; ++q) hv[q] = H4[(size_t)svc[q] * 64 + lane];
      float ex[UNR];
      #pragma unroll
      for (int q = 0; q < UNR; ++q) {
        float sc = pc[q] + s1B;
        sc = sc > 0.f ? sc : NEG_SLOPE * sc;
        ex[q] = __expf(sc);
        dsum += ex[q];
      }
#ifdef HAS_DOT2
      #pragma unroll
      for (int q = 0; q < UNR; q += 2) {
        unsigned fp;
        asm("v_cvt_pk_bf16_f32 %0, %1, %2" : "=v"(fp) : "v"(ex[q]), "v"(ex[q + 1]));
        uint2 ua = __builtin_bit_cast(uint2, hv[q]);
        uint2 ub = __builtin_bit_cast(uint2, hv[q + 1]);
        unsigned p0 = __builtin_amdgcn_perm(ua.x, ub.x, 0x01000504u);
        unsigned p1 = __builtin_amdgcn_perm(ua.x, ub.x, 0x03020706u);
        unsigned p2 = __builtin_amdgcn_perm(ua.y, ub.y, 0x01000504u);
        unsigned p3 = __builtin_amdgcn_perm(ua.y, ub.y, 0x03020706u);
        bf16x2v fv = __builtin_bit_cast(bf16x2v, fp);
        acc.x = __builtin_amdgcn_fdot2_f32_bf16(fv, __builtin_bit_cast(bf16x2v, p0), acc.x, false);
        acc.y = __builtin_amdgcn_fdot2_f32_bf16(fv, __builtin_bit_cast(bf16x2v, p1), acc.y, false);
        acc.z = __builtin_amdgcn_fdot2_f32_bf16(fv, __builtin_bit_cast(bf16x2v, p2), acc.z, false);
        acc.w = __builtin_amdgcn_fdot2_f32_bf16(fv, __builtin_bit_cast(bf16x2v, p3), acc.w, false);
      }
#else
      #pragma unroll
      for (int q = 0; q < UNR; ++q) {
        acc.x += ex[q] * bf2f(hv[q][0]);
        acc.y += ex[q] * bf2f(hv[q][1]);
        acc.z += ex[q] * bf2f(hv[q][2]);
        acc.w += ex[q] * bf2f(hv[q][3]);
      }
#endif
      #pragma unroll
      for (int q = 0; q < UNR; ++q) { svc[q] = svn[q]; pc[q] = pn[q]; }
    }
    float inv = 1.f / (dsum + EPS_F);
    tot.x += acc.x * inv; tot.y += acc.y * inv;
    tot.z += acc.z * inv; tot.w += acc.w * inv;
  }
  u16x4 ob;
  ob[0] = f2bf_rtn(tot.x); ob[1] = f2bf_rtn(tot.y);
  ob[2] = f2bf_rtn(tot.z); ob[3] = f2bf_rtn(tot.w);
  reinterpret_cast<u16x4*>(Hsb)[(size_t)v * 64 + lane] = ob;
}

// ---------- bf16 Hsum -> transposed bf16: Bt[h][k], K padded ----------
__global__ __launch_bounds__(256) void k_cvt_B(
    const unsigned short* __restrict__ Hsb, unsigned short* __restrict__ Bthi) {
  __shared__ unsigned short tile[64][68];
  const int t = threadIdx.x;
  const int v0 = blockIdx.x * 64;
  const int h0 = blockIdx.y * 64;
  #pragma unroll
  for (int it = 0; it < 4; ++it) {
    int task = t + it * 256;
    int vloc = task >> 4, cg = task & 15;
    int v = v0 + vloc;
    u16x4 val = {0, 0, 0, 0};
    if (v < V_N)
      val = *reinterpret_cast<const u16x4*>(Hsb + (size_t)v * HID + h0 + cg * 4);
    *reinterpret_cast<u16x4*>(&tile[vloc][cg * 4]) = val;
  }
  __syncthreads();
  #pragma unroll
  for (int it = 0; it < 4; ++it) {
    int task = t + it * 256;
    int hloc = task >> 4, vg = task & 15;
    u16x4 o;
    o[0] = tile[vg * 4 + 0][hloc];
    o[1] = tile[vg * 4 + 1][hloc];
    o[2] = tile[vg * 4 + 2][hloc];
    o[3] = tile[vg * 4 + 3][hloc];
    *reinterpret_cast<u16x4*>(Bthi + (size_t)(h0 + hloc) * K_PAD + v0 + vg * 4) = o;
  }
}

// ---------- Big GEMM: LDS A staging + B register double-buffer, counted vmcnt ----------
__global__ __launch_bounds__(512, 4) void k_gemm1_mfma(
    const unsigned short* __restrict__ Xhi,
    const unsigned short* __restrict__ Bthi,
    float* __restrict__ part) {
  __shared__ __align__(16) unsigned short Alds[2][8][2048];  // 64 KB
  const int bid = blockIdx.x;
  const int xcd = bid & 7;
  const int slot = bid >> 3;
  const int w = xcd * 94 + slot;       // bijective for 752
  const int zb = w >> 4;               // 0..46 K-chunk
  const int xb = w & 15;               // 0..15 M-block
  const int lane = threadIdx.x & 63;
  const int wave = threadIdx.x >> 6;   // 0..7
  const int mw = wave >> 2;            // 0..1
  const int nw = wave & 3;             // 0..3
  const int m0 = xb * 64;
  const int n0 = nw * 64;
  const int r = lane & 15;
  const int koff = lane >> 4;          // 0..3
  const int kel0 = zb * CHUNK_EL;
  const int xr = r & 7;

  const unsigned short* gsrc =
      Xhi + (size_t)(m0 + mw * 32 + (lane >> 3)) * K_PAD + kel0 + (lane & 7) * 8;
  unsigned short* l0 = &Alds[0][wave][0];
  unsigned short* l1 = &Alds[1][wave][0];

  const unsigned short* Bh[4];
  #pragma unroll
  for (int j = 0; j < 4; ++j)
    Bh[j] = Bthi + (size_t)(n0 + 16 * j + r) * K_PAD + kel0 + koff * 8;

  // prologue: stage A(0) + load B(0) into regs
  #pragma unroll
  for (int q = 0; q < 4; ++q)
    gload_lds16(gsrc + (size_t)q * 8 * K_PAD, l0 + q * 512);
  bf16x8 bcur[8];
  #pragma unroll
  for (int j = 0; j < 4; ++j) {
    bcur[j]     = *reinterpret_cast<const bf16x8*>(Bh[j]);
    bcur[4 + j] = *reinterpret_cast<const bf16x8*>(Bh[j] + 32);
  }

  f32x4 acc[2][4] = {};
  for (int t = 0; t < NSTEP; ++t) {
    const unsigned short* cur = (t & 1) ? l1 : l0;
    unsigned short* nxt = (t & 1) ? l0 : l1;
    bf16x8 bnxt[8];
    if (t + 1 < NSTEP) {
      #pragma unroll
      for (int q = 0; q < 4; ++q)
        gload_lds16(gsrc + (t + 1) * 64 + (size_t)q * 8 * K_PAD, nxt + q * 512);
      const int noff = (t + 1) * 64;
      #pragma unroll
      for (int j = 0; j < 4; ++j) {
        bnxt[j]     = *reinterpret_cast<const bf16x8*>(Bh[j] + noff);
        bnxt[4 + j] = *reinterpret_cast<const bf16x8*>(Bh[j] + noff + 32);
      }
      asm volatile("s_waitcnt vmcnt(12)" ::: "memory");  // drain stage(t)+B(t) only
    } else {
      asm volatile("s_waitcnt vmcnt(0)" ::: "memory");
    }
    __builtin_amdgcn_sched_barrier(0);
    {
      const int gr = (koff ^ xr) * 8;
      bf16x8 a0 = *reinterpret_cast<const bf16x8*>(cur + r * 64 + gr);
      bf16x8 a1 = *reinterpret_cast<const bf16x8*>(cur + (16 + r) * 64 + gr);
      #pragma unroll
      for (int j = 0; j < 4; ++j) {
        acc[0][j] = __builtin_amdgcn_mfma_f32_16x16x32_bf16(a0, bcur[j], acc[0][j], 0, 0, 0);
        acc[1][j] = __builtin_amdgcn_mfma_f32_16x16x32_bf16(a1, bcur[j], acc[1][j], 0, 0, 0);
      }
    }
    {
      const int gr = ((4 + koff) ^ xr) * 8;
      bf16x8 a0 = *reinterpret_cast<const bf16x8*>(cur + r * 64 + gr);
      bf16x8 a1 = *reinterpret_cast<const bf16x8*>(cur + (16 + r) * 64 + gr);
      #pragma unroll
      for (int j = 0; j < 4; ++j) {
        acc[0][j] = __builtin_amdgcn_mfma_f32_16x16x32_bf16(a0, bcur[4 + j], acc[0][j], 0, 0, 0);
        acc[1][j] = __builtin_amdgcn_mfma_f32_16x16x32_bf16(a1, bcur[4 + j], acc[1][j], 0, 0, 0);
      }
    }
    if (t + 1 < NSTEP) {
      #pragma unroll
      for (int j = 0; j < 8; ++j) bcur[j] = bnxt[j];
    }
  }
  float* pw = part + (size_t)w * (64 * 256);
  #pragma unroll
  for (int i = 0; i < 2; ++i) {
    int rloc = mw * 32 + 16 * i + koff * 4;
    #pragma unroll
    for (int j = 0; j < 4; ++j) {
      int colg = n0 + 16 * j + r;
      #pragma unroll
      for (int jj = 0; jj < 4; ++jj)
        pw[(size_t)(rloc + jj) * 256 + colg] = acc[i][j][jj];
    }
  }
}

// ---------- fused reduce(47 partials) + out = fused @ fc_w^T + fc_b ----------
__global__ __launch_bounds__(256) void k_gemm2(
    const float* __restrict__ part, const float* __restrict__ fc_w,
    const float* __restrict__ fc_b, float* __restrict__ out) {
  int bd = blockIdx.x, o = threadIdx.x;
  const int xb = bd >> 6, rl = bd & 63;
  float s = 0.f;
  #pragma unroll 4
  for (int zb = 0; zb < SK_MFMA; ++zb)
    s += part[((size_t)(zb * 16 + xb) * 64 + rl) * 256 + o];
  __shared__ float fs[HID];
  fs[o] = s;
  __syncthreads();
  float acc = fc_b[o];
  const float* wr = fc_w + (size_t)o * HID;
  #pragma unroll 8
  for (int h = 0; h < HID; ++h) acc += fs[h] * wr[h];
  out[(size_t)bd * HID + o] = acc;
}

extern "C" void kernel_launch(void* const* d_in, const int* in_sizes, int n_in,
                              void* d_out, int out_size, void* d_ws, size_t ws_size,
                              hipStream_t stream) {
  const float* X    = (const float*)d_in[0];
  const float* W0   = (const float*)d_in[1];
  const float* a0   = (const float*)d_in[2];
  const float* W1   = (const float*)d_in[3];
  const float* a1   = (const float*)d_in[4];
  const float* fc_w = (const float*)d_in[5];
  const float* fc_b = (const float*)d_in[6];
  const float* val0 = (const float*)d_in[7];
  const float* val1 = (const float*)d_in[8];
  const int*   src0 = (const int*)d_in[9];
  const int*   dst0 = (const int*)d_in[10];
  const int*   src1 = (const int*)d_in[11];
  const int*   dst1 = (const int*)d_in[12];
  float* out = (float*)d_out;

  char* ws = (char*)d_ws;
  size_t off = 0;
  auto alloc = [&](size_t bytes) {
    void* p = ws + off;
    off += (bytes + 255) & ~(size_t)255;
    return p;
  };
  int*   cnt   = (int*)alloc(4 * (size_t)V_N * 4);                         // 480 KB
  int2*  csr_s = (int2*)alloc(2 * (size_t)V_N * SLOTS * 8);                // 30.7 MB
  int*   csr_d = (int*)alloc(2 * (size_t)V_N * SLOTS * 4);                 // 15.4 MB
  unsigned short* Hb  = (unsigned short*)alloc(2 * (size_t)V_N * HID * 2); // 30.7 MB
  unsigned short* Wb0 = (unsigned short*)alloc((size_t)V_N * HID * 2);     // 15.4 MB
  unsigned short* Wb1 = (unsigned short*)alloc((size_t)V_N * HID * 2);
  unsigned short* Hsb = (unsigned short*)alloc((size_t)V_N * HID * 2);     // 15.4 MB
  float* s0    = (float*)alloc(2 * (size_t)V_N * HEADS * 4);
  float* s1    = (float*)alloc(2 * (size_t)V_N * HEADS * 4);
  unsigned short* Xhi  = (unsigned short*)alloc((size_t)M_ROWS * K_PAD * 2);
  unsigned short* Bthi = (unsigned short*)alloc((size_t)HID * K_PAD * 2);
  // GEMM partials (49.3 MB) alias csr_d(15.4)+Hb(30.7)+Wb0(15.4) — dead by GEMM time
  float* part = (float*)csr_d;

  hipMemsetAsync(cnt, 0, 4 * (size_t)V_N * 4, stream);

  k_fill_cvt<<<22500 + XBLK, 256, 0, stream>>>(
      src0, dst0, src1, dst1, val0, val1, cnt, csr_s, csr_d,
      W0, W1, Wb0, Wb1, X, Xhi);

  const int VB = (V_N + 3) / 4;       // 7500
  k_gather_H<<<dim3(VB, 2), 256, 0, stream>>>(cnt, csr_s, Wb0, Wb1, a0, a1,
                                              Hb, s0, s1);
  k_fused_agg<<<VB, 256, 0, stream>>>(cnt, csr_d, s0, s1, Hb, Hsb);

  k_cvt_B<<<dim3(K_PAD / 64, HID / 64), 256, 0, stream>>>(Hsb, Bthi);
  k_gemm1_mfma<<<8 * 94, 512, 0, stream>>>(Xhi, Bthi, part);
  k_gemm2<<<M_ROWS, 256, 0, stream>>>(part, fc_w, fc_b, out);
}

// Round 26
// 448.983 us; speedup vs baseline: 1.0195x; 1.0195x over previous
//
#include <hip/hip_runtime.h>
#include <hip/hip_bf16.h>
#include <cstddef>

#define V_N 30000
#define E_N 480000
#define HID 256
#define HEADS 4
#define HD 64
#define M_ROWS 1024   // 2*512
#define K_DIM 30000
#define K_PAD 30080   // 47 * 640
#define CHUNK_EL 640  // K elements per GEMM block
#define NSTEP 10      // 640 / 64
#define SK_MFMA 47
#define NR 8          // owner ranges (XCD-owned writes)
#define VR (V_N / NR) // 3750
#define UNR 8         // gather MLP depth
#define SLOTS 64      // fixed CSR arena slots per vertex (mean deg 16, sigma 4)
#define GRAN (K_PAD / 8)          // 3760 granules per X row
#define XTASKS (M_ROWS * GRAN)    // cvt_X granule tasks
#define NEG_SLOPE 0.2f
#define EPS_F 1e-9f

#if defined(__has_builtin)
#if __has_builtin(__builtin_amdgcn_fdot2_f32_bf16) && __has_builtin(__builtin_amdgcn_perm)
#define HAS_DOT2 1
#endif
#endif

typedef __attribute__((ext_vector_type(8))) short bf16x8;
typedef __attribute__((ext_vector_type(4))) float f32x4;
typedef __attribute__((ext_vector_type(8))) unsigned short u16x8;
typedef __attribute__((ext_vector_type(4))) unsigned short u16x4;
#ifdef HAS_DOT2
typedef __attribute__((ext_vector_type(2))) __bf16 bf16x2v;
#endif

__device__ inline unsigned short f2bf_rtn(float f) {
  unsigned u = __float_as_uint(f);
  unsigned r = u + 0x7fffu + ((u >> 16) & 1u);
  return (unsigned short)(r >> 16);
}
__device__ inline float bf2f(unsigned short h) {
  return __uint_as_float(((unsigned)h) << 16);
}

__device__ __forceinline__ void gload_lds16(const void* g, void* l) {
  __builtin_amdgcn_global_load_lds(
      (const __attribute__((address_space(1))) void*)g,
      (__attribute__((address_space(3))) void*)l, 16, 0, 0);
}

// ---------- single-pass CSR arena fill (XCD-owned ranges) + cvt_W fused ----------
__global__ __launch_bounds__(256) void k_fill_cvtW(
    const int* __restrict__ s0g, const int* __restrict__ d0g,
    const int* __restrict__ s1g, const int* __restrict__ d1g,
    const float* __restrict__ val0, const float* __restrict__ val1,
    int* __restrict__ cnt, int2* __restrict__ csr_s, int* __restrict__ csr_d,
    const float* __restrict__ W0src, const float* __restrict__ W1src,
    unsigned short* __restrict__ W0dst, unsigned short* __restrict__ W1dst) {
  const int bid = blockIdx.x;
  if (bid < 15000) {
    const int r = bid & 7;
    const int e = (bid >> 3) * 256 + threadIdx.x;
    if (e >= E_N) return;
    const int v0 = r * VR, v1 = v0 + VR;
    int k, p;
    k = s0g[e];
    if (k >= v0 && k < v1) {
      p = atomicAdd(&cnt[0 * V_N + k], 1);
      if (p < SLOTS) csr_s[((size_t)0 * V_N + k) * SLOTS + p] = make_int2(d0g[e], __float_as_int(val0[e]));
    }
    k = d0g[e];
    if (k >= v0 && k < v1) {
      p = atomicAdd(&cnt[1 * V_N + k], 1);
      if (p < SLOTS) csr_d[((size_t)0 * V_N + k) * SLOTS + p] = s0g[e];
    }
    k = s1g[e];
    if (k >= v0 && k < v1) {
      p = atomicAdd(&cnt[2 * V_N + k], 1);
      if (p < SLOTS) csr_s[((size_t)1 * V_N + k) * SLOTS + p] = make_int2(d1g[e], __float_as_int(val1[e]));
    }
    k = d1g[e];
    if (k >= v0 && k < v1) {
      p = atomicAdd(&cnt[3 * V_N + k], 1);
      if (p < SLOTS) csr_d[((size_t)1 * V_N + k) * SLOTS + p] = s1g[e];
    }
  } else {
    const int b = bid - 15000;          // 0..7499
    const int wg = b % 3750;
    const int g = b / 3750;
    const float* Wsrc = g ? W1src : W0src;
    unsigned short* Wdst = g ? W1dst : W0dst;
    size_t i = ((size_t)wg * 256 + threadIdx.x) * 8;
    const float4* p = reinterpret_cast<const float4*>(Wsrc + i);
    float4 x0 = p[0], x1 = p[1];
    float xs[8] = {x0.x, x0.y, x0.z, x0.w, x1.x, x1.y, x1.z, x1.w};
    u16x8 o;
    #pragma unroll
    for (int j = 0; j < 8; ++j) o[j] = f2bf_rtn(xs[j]);
    *reinterpret_cast<u16x8*>(Wdst + i) = o;
  }
}

// ---------- Phase 1+2: H gather (y=0,1) + cvt_X (y=2) fused ----------
__global__ __launch_bounds__(256) void k_gather_H(
    const int* __restrict__ cnt, const int2* __restrict__ csr_s,
    const unsigned short* __restrict__ Wb0, const unsigned short* __restrict__ Wb1,
    const float* __restrict__ a0v, const float* __restrict__ a1v,
    unsigned short* __restrict__ Hb, float* __restrict__ s0, float* __restrict__ s1,
    const float* __restrict__ X, unsigned short* __restrict__ Xhi) {
  if (blockIdx.y == 2) {
    #pragma unroll
    for (int it = 0; it < 3; ++it) {
      int idx = (blockIdx.x * 256 + threadIdx.x) + it * (7500 * 256);
      if (idx >= XTASKS) break;
      int row = idx / GRAN;
      int g = idx - row * GRAN;
      int k0 = g * 8;
      u16x8 hi;
      if (k0 < K_DIM) {
        const float4* p = reinterpret_cast<const float4*>(X + (size_t)row * K_DIM + k0);
        float4 x0 = p[0], x1 = p[1];
        float xs[8] = {x0.x, x0.y, x0.z, x0.w, x1.x, x1.y, x1.z, x1.w};
        #pragma unroll
        for (int j = 0; j < 8; ++j) hi[j] = f2bf_rtn(xs[j]);
      } else {
        #pragma unroll
        for (int j = 0; j < 8; ++j) hi[j] = 0;
      }
      int gs = (g & ~7) | ((g & 7) ^ (row & 7));
      *reinterpret_cast<u16x8*>(Xhi + (size_t)row * K_PAD + gs * 8) = hi;
    }
    return;
  }
  const int g = blockIdx.y;
  const unsigned short* Wb = g ? Wb1 : Wb0;
  const float* a = g ? a1v : a0v;
  unsigned short* Hbg = Hb + (size_t)g * V_N * HID;
  float* s0g = s0 + (size_t)g * V_N * HEADS;
  float* s1g = s1 + (size_t)g * V_N * HEADS;

  int v = blockIdx.x * 4 + (threadIdx.x >> 6);
  if (v >= V_N) return;
  int lane = threadIdx.x & 63;
  const int2* csr = csr_s + ((size_t)g * V_N + v) * SLOTS;
  int n = cnt[(g * 2) * V_N + v];
  n = n < SLOTS ? n : SLOTS;
  const u16x4* W4 = reinterpret_cast<const u16x4*>(Wb);
  float4 acc = {0.f, 0.f, 0.f, 0.f};
  int dcur[UNR]; float fcur[UNR];
  #pragma unroll
  for (int q = 0; q < UNR; ++q) {
    dcur[q] = 0; fcur[q] = 0.f;
    if (q < n) { int2 pl = csr[q]; dcur[q] = pl.x; fcur[q] = __int_as_float(pl.y); }
  }
  for (int i = 0; i < n; i += UNR) {
    int dnxt[UNR]; float fnxt[UNR];
    #pragma unroll
    for (int q = 0; q < UNR; ++q) {
      dnxt[q] = 0; fnxt[q] = 0.f;
      if (i + UNR + q < n) { int2 pl = csr[i + UNR + q]; dnxt[q] = pl.x; fnxt[q] = __int_as_float(pl.y); }
    }
    u16x4 wv[UNR];
    #pragma unroll
    for (int q = 0; q < UNR; ++q) wv[q] = W4[(size_t)dcur[q] * 64 + lane];
#ifdef HAS_DOT2
    #pragma unroll
    for (int q = 0; q < UNR; q += 2) {
      unsigned fp;
      asm("v_cvt_pk_bf16_f32 %0, %1, %2" : "=v"(fp) : "v"(fcur[q]), "v"(fcur[q + 1]));
      uint2 ua = __builtin_bit_cast(uint2, wv[q]);
      uint2 ub = __builtin_bit_cast(uint2, wv[q + 1]);
      unsigned p0 = __builtin_amdgcn_perm(ua.x, ub.x, 0x01000504u);
      unsigned p1 = __builtin_amdgcn_perm(ua.x, ub.x, 0x03020706u);
      unsigned p2 = __builtin_amdgcn_perm(ua.y, ub.y, 0x01000504u);
      unsigned p3 = __builtin_amdgcn_perm(ua.y, ub.y, 0x03020706u);
      bf16x2v fv = __builtin_bit_cast(bf16x2v, fp);
      acc.x = __builtin_amdgcn_fdot2_f32_bf16(fv, __builtin_bit_cast(bf16x2v, p0), acc.x, false);
      acc.y = __builtin_amdgcn_fdot2_f32_bf16(fv, __builtin_bit_cast(bf16x2v, p1), acc.y, false);
      acc.z = __builtin_amdgcn_fdot2_f32_bf16(fv, __builtin_bit_cast(bf16x2v, p2), acc.z, false);
      acc.w = __builtin_amdgcn_fdot2_f32_bf16(fv, __builtin_bit_cast(bf16x2v, p3), acc.w, false);
    }
#else
    #pragma unroll
    for (int q = 0; q < UNR; ++q) {
      acc.x += fcur[q] * bf2f(wv[q][0]);
      acc.y += fcur[q] * bf2f(wv[q][1]);
      acc.z += fcur[q] * bf2f(wv[q][2]);
      acc.w += fcur[q] * bf2f(wv[q][3]);
    }
#endif
    #pragma unroll
    for (int q = 0; q < UNR; ++q) { dcur[q] = dnxt[q]; fcur[q] = fnxt[q]; }
  }
  u16x4 hb;
  hb[0] = f2bf_rtn(acc.x); hb[1] = f2bf_rtn(acc.y);
  hb[2] = f2bf_rtn(acc.z); hb[3] = f2bf_rtn(acc.w);
  *(reinterpret_cast<u16x4*>(Hbg) + (size_t)v * 64 + lane) = hb;
  int h = lane >> 4, dd = (lane & 15) * 4;
  const float* ah = a + h * (2 * HD);
  float p0 = acc.x * ah[dd] + acc.y * ah[dd + 1] + acc.z * ah[dd + 2] + acc.w * ah[dd + 3];
  float p1 = acc.x * ah[HD + dd] + acc.y * ah[HD + dd + 1] + acc.z * ah[HD + dd + 2] + acc.w * ah[HD + dd + 3];
  #pragma unroll
  for (int off = 1; off < 16; off <<= 1) {
    p0 += __shfl_xor(p0, off);
    p1 += __shfl_xor(p1, off);
  }
  if ((lane & 15) == 0) {
    s0g[v * HEADS + h] = p0;
    s1g[v * HEADS + h] = p1;
  }
}

// ---------- Phase 3+4: softmax + aggregation; writes bf16 Hsum directly ----------
__global__ __launch_bounds__(256) void k_fused_agg(
    const int* __restrict__ cnt, const int* __restrict__ csr_d,
    const float* __restrict__ s0, const float* __restrict__ s1,
    const unsigned short* __restrict__ Hb, unsigned short* __restrict__ Hsb) {
  int v = blockIdx.x * 4 + (threadIdx.x >> 6);
  if (v >= V_N) return;
  int lane = threadIdx.x & 63;
  int hB = lane >> 4;
  float4 tot = {0.f, 0.f, 0.f, 0.f};
  #pragma unroll 1
  for (int g = 0; g < 2; ++g) {
    const int* csr = csr_d + ((size_t)g * V_N + v) * SLOTS;
    const float* s0g = s0 + (size_t)g * V_N * HEADS;
    const u16x4* H4 = reinterpret_cast<const u16x4*>(Hb + (size_t)g * V_N * HID);
    const float s1B = s1[(size_t)g * V_N * HEADS + v * HEADS + hB];
    int n = cnt[(g * 2 + 1) * V_N + v];
    n = n < SLOTS ? n : SLOTS;
    float4 acc = {0.f, 0.f, 0.f, 0.f};
    float dsum = 0.f;
    int svc[UNR]; float pc[UNR];
    #pragma unroll
    for (int q = 0; q < UNR; ++q) {
      svc[q] = 0; pc[q] = -1e30f;
      if (q < n) { svc[q] = csr[q]; pc[q] = s0g[svc[q] * HEADS + hB]; }
    }
    for (int i = 0; i < n; i += UNR) {
      int svn[UNR]; float pn[UNR];
      #pragma unroll
      for (int q = 0; q < UNR; ++q) {
        svn[q] = 0; pn[q] = -1e30f;
        if (i + UNR + q < n) { svn[q] = csr[i + UNR + q]; pn[q] = s0g[svn[q] * HEADS + hB]; }
      }
      u16x4 hv[UNR];
      #pragma unroll
      for (int q = 0; q < UNR; ++q) hv[q] = H4[(size_t)svc[q] * 64 + lane];
      float ex[UNR];
      #pragma unroll
      for (int q = 0; q < UNR; ++q) {
        float sc = pc[q] + s1B;
        sc = sc > 0.f ? sc : NEG_SLOPE * sc;
        ex[q] = __expf(sc);
        dsum += ex[q];
      }
#ifdef HAS_DOT2
      #pragma unroll
      for (int q = 0; q < UNR; q += 2) {
        unsigned fp;
        asm("v_cvt_pk_bf16_f32 %0, %1, %2" : "=v"(fp) : "v"(ex[q]), "v"(ex[q + 1]));
        uint2 ua = __builtin_bit_cast(uint2, hv[q]);
        uint2 ub = __builtin_bit_cast(uint2, hv[q + 1]);
        unsigned p0 = __builtin_amdgcn_perm(ua.x, ub.x, 0x01000504u);
        unsigned p1 = __builtin_amdgcn_perm(ua.x, ub.x, 0x03020706u);
        unsigned p2 = __builtin_amdgcn_perm(ua.y, ub.y, 0x01000504u);
        unsigned p3 = __builtin_amdgcn_perm(ua.y, ub.y, 0x03020706u);
        bf16x2v fv = __builtin_bit_cast(bf16x2v, fp);
        acc.x = __builtin_amdgcn_fdot2_f32_bf16(fv, __builtin_bit_cast(bf16x2v, p0), acc.x, false);
        acc.y = __builtin_amdgcn_fdot2_f32_bf16(fv, __builtin_bit_cast(bf16x2v, p1), acc.y, false);
        acc.z = __builtin_amdgcn_fdot2_f32_bf16(fv, __builtin_bit_cast(bf16x2v, p2), acc.z, false);
        acc.w = __builtin_amdgcn_fdot2_f32_bf16(fv, __builtin_bit_cast(bf16x2v, p3), acc.w, false);
      }
#else
      #pragma unroll
      for (int q = 0; q < UNR; ++q) {
        acc.x += ex[q] * bf2f(hv[q][0]);
        acc.y += ex[q] * bf2f(hv[q][1]);
        acc.z += ex[q] * bf2f(hv[q][2]);
        acc.w += ex[q] * bf2f(hv[q][3]);
      }
#endif
      #pragma unroll
      for (int q = 0; q < UNR; ++q) { svc[q] = svn[q]; pc[q] = pn[q]; }
    }
    float inv = 1.f / (dsum + EPS_F);
    tot.x += acc.x * inv; tot.y += acc.y * inv;
    tot.z += acc.z * inv; tot.w += acc.w * inv;
  }
  u16x4 ob;
  ob[0] = f2bf_rtn(tot.x); ob[1] = f2bf_rtn(tot.y);
  ob[2] = f2bf_rtn(tot.z); ob[3] = f2bf_rtn(tot.w);
  reinterpret_cast<u16x4*>(Hsb)[(size_t)v * 64 + lane] = ob;
}

// ---------- bf16 Hsum -> transposed bf16: Bt[h][k], K padded ----------
__global__ __launch_bounds__(256) void k_cvt_B(
    const unsigned short* __restrict__ Hsb, unsigned short* __restrict__ Bthi) {
  __shared__ unsigned short tile[64][68];
  const int t = threadIdx.x;
  const int v0 = blockIdx.x * 64;
  const int h0 = blockIdx.y * 64;
  #pragma unroll
  for (int it = 0; it < 4; ++it) {
    int task = t + it * 256;
    int vloc = task >> 4, cg = task & 15;
    int v = v0 + vloc;
    u16x4 val = {0, 0, 0, 0};
    if (v < V_N)
      val = *reinterpret_cast<const u16x4*>(Hsb + (size_t)v * HID + h0 + cg * 4);
    *reinterpret_cast<u16x4*>(&tile[vloc][cg * 4]) = val;
  }
  __syncthreads();
  #pragma unroll
  for (int it = 0; it < 4; ++it) {
    int task = t + it * 256;
    int hloc = task >> 4, vg = task & 15;
    u16x4 o;
    o[0] = tile[vg * 4 + 0][hloc];
    o[1] = tile[vg * 4 + 1][hloc];
    o[2] = tile[vg * 4 + 2][hloc];
    o[3] = tile[vg * 4 + 3][hloc];
    *reinterpret_cast<u16x4*>(Bthi + (size_t)(h0 + hloc) * K_PAD + v0 + vg * 4) = o;
  }
}

// ---------- Big GEMM: LDS A staging + B register double-buffer, counted vmcnt ----------
__global__ __launch_bounds__(512, 4) void k_gemm1_mfma(
    const unsigned short* __restrict__ Xhi,
    const unsigned short* __restrict__ Bthi,
    float* __restrict__ part) {
  __shared__ __align__(16) unsigned short Alds[2][8][2048];  // 64 KB
  const int bid = blockIdx.x;
  const int xcd = bid & 7;
  const int slot = bid >> 3;
  const int w = xcd * 94 + slot;       // bijective for 752
  const int zb = w >> 4;               // 0..46 K-chunk
  const int xb = w & 15;               // 0..15 M-block
  const int lane = threadIdx.x & 63;
  const int wave = threadIdx.x >> 6;   // 0..7
  const int mw = wave >> 2;            // 0..1
  const int nw = wave & 3;             // 0..3
  const int m0 = xb * 64;
  const int n0 = nw * 64;
  const int r = lane & 15;
  const int koff = lane >> 4;          // 0..3
  const int kel0 = zb * CHUNK_EL;
  const int xr = r & 7;

  const unsigned short* gsrc =
      Xhi + (size_t)(m0 + mw * 32 + (lane >> 3)) * K_PAD + kel0 + (lane & 7) * 8;
  unsigned short* l0 = &Alds[0][wave][0];
  unsigned short* l1 = &Alds[1][wave][0];

  const unsigned short* Bh[4];
  #pragma unroll
  for (int j = 0; j < 4; ++j)
    Bh[j] = Bthi + (size_t)(n0 + 16 * j + r) * K_PAD + kel0 + koff * 8;

  // prologue: stage A(0) + load B(0) into regs
  #pragma unroll
  for (int q = 0; q < 4; ++q)
    gload_lds16(gsrc + (size_t)q * 8 * K_PAD, l0 + q * 512);
  bf16x8 bcur[8];
  #pragma unroll
  for (int j = 0; j < 4; ++j) {
    bcur[j]     = *reinterpret_cast<const bf16x8*>(Bh[j]);
    bcur[4 + j] = *reinterpret_cast<const bf16x8*>(Bh[j] + 32);
  }

  f32x4 acc[2][4] = {};
  for (int t = 0; t < NSTEP; ++t) {
    const unsigned short* cur = (t & 1) ? l1 : l0;
    unsigned short* nxt = (t & 1) ? l0 : l1;
    bf16x8 bnxt[8];
    if (t + 1 < NSTEP) {
      #pragma unroll
      for (int q = 0; q < 4; ++q)
        gload_lds16(gsrc + (t + 1) * 64 + (size_t)q * 8 * K_PAD, nxt + q * 512);
      const int noff = (t + 1) * 64;
      #pragma unroll
      for (int j = 0; j < 4; ++j) {
        bnxt[j]     = *reinterpret_cast<const bf16x8*>(Bh[j] + noff);
        bnxt[4 + j] = *reinterpret_cast<const bf16x8*>(Bh[j] + noff + 32);
      }
      asm volatile("s_waitcnt vmcnt(12)" ::: "memory");  // drain stage(t)+B(t) only
    } else {
      asm volatile("s_waitcnt vmcnt(0)" ::: "memory");
    }
    __builtin_amdgcn_sched_barrier(0);
    {
      const int gr = (koff ^ xr) * 8;
      bf16x8 a0 = *reinterpret_cast<const bf16x8*>(cur + r * 64 + gr);
      bf16x8 a1 = *reinterpret_cast<const bf16x8*>(cur + (16 + r) * 64 + gr);
      #pragma unroll
      for (int j = 0; j < 4; ++j) {
        acc[0][j] = __builtin_amdgcn_mfma_f32_16x16x32_bf16(a0, bcur[j], acc[0][j], 0, 0, 0);
        acc[1][j] = __builtin_amdgcn_mfma_f32_16x16x32_bf16(a1, bcur[j], acc[1][j], 0, 0, 0);
      }
    }
    {
      const int gr = ((4 + koff) ^ xr) * 8;
      bf16x8 a0 = *reinterpret_cast<const bf16x8*>(cur + r * 64 + gr);
      bf16x8 a1 = *reinterpret_cast<const bf16x8*>(cur + (16 + r) * 64 + gr);
      #pragma unroll
      for (int j = 0; j < 4; ++j) {
        acc[0][j] = __builtin_amdgcn_mfma_f32_16x16x32_bf16(a0, bcur[4 + j], acc[0][j], 0, 0, 0);
        acc[1][j] = __builtin_amdgcn_mfma_f32_16x16x32_bf16(a1, bcur[4 + j], acc[1][j], 0, 0, 0);
      }
    }
    if (t + 1 < NSTEP) {
      #pragma unroll
      for (int j = 0; j < 8; ++j) bcur[j] = bnxt[j];
    }
  }
  float* pw = part + (size_t)w * (64 * 256);
  #pragma unroll
  for (int i = 0; i < 2; ++i) {
    int rloc = mw * 32 + 16 * i + koff * 4;
    #pragma unroll
    for (int j = 0; j < 4; ++j) {
      int colg = n0 + 16 * j + r;
      #pragma unroll
      for (int jj = 0; jj < 4; ++jj)
        pw[(size_t)(rloc + jj) * 256 + colg] = acc[i][j][jj];
    }
  }
}

// ---------- fused reduce(47 partials) + out = fused @ fc_w^T + fc_b ----------
__global__ __launch_bounds__(256) void k_gemm2(
    const float* __restrict__ part, const float* __restrict__ fc_w,
    const float* __restrict__ fc_b, float* __restrict__ out) {
  int bd = blockIdx.x, o = threadIdx.x;
  const int xb = bd >> 6, rl = bd & 63;
  float s = 0.f;
  #pragma unroll 4
  for (int zb = 0; zb < SK_MFMA; ++zb)
    s += part[((size_t)(zb * 16 + xb) * 64 + rl) * 256 + o];
  __shared__ float fs[HID];
  fs[o] = s;
  __syncthreads();
  float acc = fc_b[o];
  const float* wr = fc_w + (size_t)o * HID;
  #pragma unroll 8
  for (int h = 0; h < HID; ++h) acc += fs[h] * wr[h];
  out[(size_t)bd * HID + o] = acc;
}

extern "C" void kernel_launch(void* const* d_in, const int* in_sizes, int n_in,
                              void* d_out, int out_size, void* d_ws, size_t ws_size,
                              hipStream_t stream) {
  const float* X    = (const float*)d_in[0];
  const float* W0   = (const float*)d_in[1];
  const float* a0   = (const float*)d_in[2];
  const float* W1   = (const float*)d_in[3];
  const float* a1   = (const float*)d_in[4];
  const float* fc_w = (const float*)d_in[5];
  const float* fc_b = (const float*)d_in[6];
  const float* val0 = (const float*)d_in[7];
  const float* val1 = (const float*)d_in[8];
  const int*   src0 = (const int*)d_in[9];
  const int*   dst0 = (const int*)d_in[10];
  const int*   src1 = (const int*)d_in[11];
  const int*   dst1 = (const int*)d_in[12];
  float* out = (float*)d_out;

  char* ws = (char*)d_ws;
  size_t off = 0;
  auto alloc = [&](size_t bytes) {
    void* p = ws + off;
    off += (bytes + 255) & ~(size_t)255;
    return p;
  };
  int*   cnt   = (int*)alloc(4 * (size_t)V_N * 4);                         // 480 KB
  int2*  csr_s = (int2*)alloc(2 * (size_t)V_N * SLOTS * 8);                // 30.7 MB
  int*   csr_d = (int*)alloc(2 * (size_t)V_N * SLOTS * 4);                 // 15.4 MB
  unsigned short* Hb  = (unsigned short*)alloc(2 * (size_t)V_N * HID * 2); // 30.7 MB
  unsigned short* Wb0 = (unsigned short*)alloc((size_t)V_N * HID * 2);     // 15.4 MB
  unsigned short* Wb1 = (unsigned short*)alloc((size_t)V_N * HID * 2);
  unsigned short* Hsb = (unsigned short*)alloc((size_t)V_N * HID * 2);     // 15.4 MB
  float* s0    = (float*)alloc(2 * (size_t)V_N * HEADS * 4);
  float* s1    = (float*)alloc(2 * (size_t)V_N * HEADS * 4);
  unsigned short* Xhi  = (unsigned short*)alloc((size_t)M_ROWS * K_PAD * 2);
  unsigned short* Bthi = (unsigned short*)alloc((size_t)HID * K_PAD * 2);
  // GEMM partials (49.3 MB) alias csr_d(15.4)+Hb(30.7)+Wb0(15.4) — dead by GEMM time
  float* part = (float*)csr_d;

  hipMemsetAsync(cnt, 0, 4 * (size_t)V_N * 4, stream);

  const int EB = (E_N + 255) / 256;   // 1875
  k_fill_cvtW<<<EB * NR + 7500, 256, 0, stream>>>(
      src0, dst0, src1, dst1, val0, val1, cnt, csr_s, csr_d, W0, W1, Wb0, Wb1);

  const int VB = (V_N + 3) / 4;       // 7500
  k_gather_H<<<dim3(VB, 3), 256, 0, stream>>>(cnt, csr_s, Wb0, Wb1, a0, a1,
                                              Hb, s0, s1, X, Xhi);
  k_fused_agg<<<VB, 256, 0, stream>>>(cnt, csr_d, s0, s1, Hb, Hsb);

  k_cvt_B<<<dim3(K_PAD / 64, HID / 64), 256, 0, stream>>>(Hsb, Bthi);
  k_gemm1_mfma<<<8 * 94, 512, 0, stream>>>(Xhi, Bthi, part);
  k_gemm2<<<M_ROWS, 256, 0, stream>>>(part, fc_w, fc_b, out);
}